// Round 1
// baseline (511.331 us; speedup 1.0000x reference)
//
#include <hip/hip_runtime.h>

// BigraphLightModel — R6: degree-balanced SpMM.
//   R5 profile: k_spmm8_final(g2) 50us @ 44% HBM, VALUBusy 22%, Occ 59% —
//   wave time = max of 8 Poisson(6) row degrees (~11) vs mean 6.
//   This round:
//    (a) 64-bin counting sort of rows by in-degree (LDS-privatized hist,
//        1-wave bin scan, scatter) -> perm[] + permuted CSR bounds rrp[];
//        SpMM waves now process equal-degree rows (balanced).
//    (b) unroll-4 gather loop (2x outstanding 16B gathers per wave).
//    (c) finals consume x0 in bf16: g1 final drops its 25.6MB fp32 write
//        (only consumer was g2 final's x0 read); g2 final reads xb0_u bf16
//        (-25.6MB fetch).
//   k_cnt_rank (atomic-bound, 2x ~50us) intentionally untouched this round.

#define D       64
#define N_II    100000
#define N_UIU   200000
#define E_II    600000
#define E_UIU   1200000
#define N_USERS 100000

// ---------- bf16 helpers ----------
__device__ __forceinline__ unsigned short f2bf(float f) {
    unsigned u = __float_as_uint(f);
    u += 0x7fffu + ((u >> 16) & 1u);          // round-to-nearest-even
    return (unsigned short)(u >> 16);
}
__device__ __forceinline__ void bf8_fma(float acc[8], uint4 p, float v) {
    acc[0] += v * __uint_as_float(p.x << 16);
    acc[1] += v * __uint_as_float(p.x & 0xffff0000u);
    acc[2] += v * __uint_as_float(p.y << 16);
    acc[3] += v * __uint_as_float(p.y & 0xffff0000u);
    acc[4] += v * __uint_as_float(p.z << 16);
    acc[5] += v * __uint_as_float(p.z & 0xffff0000u);
    acc[6] += v * __uint_as_float(p.w << 16);
    acc[7] += v * __uint_as_float(p.w & 0xffff0000u);
}
__device__ __forceinline__ void bf8_add(float acc[8], uint4 p) {
    acc[0] += __uint_as_float(p.x << 16);
    acc[1] += __uint_as_float(p.x & 0xffff0000u);
    acc[2] += __uint_as_float(p.y << 16);
    acc[3] += __uint_as_float(p.y & 0xffff0000u);
    acc[4] += __uint_as_float(p.z << 16);
    acc[5] += __uint_as_float(p.z & 0xffff0000u);
    acc[6] += __uint_as_float(p.w << 16);
    acc[7] += __uint_as_float(p.w & 0xffff0000u);
}
__device__ __forceinline__ uint4 pack8(const float a[8]) {
    uint4 r;
    r.x = (unsigned)f2bf(a[0]) | ((unsigned)f2bf(a[1]) << 16);
    r.y = (unsigned)f2bf(a[2]) | ((unsigned)f2bf(a[3]) << 16);
    r.z = (unsigned)f2bf(a[4]) | ((unsigned)f2bf(a[5]) << 16);
    r.w = (unsigned)f2bf(a[6]) | ((unsigned)f2bf(a[7]) << 16);
    return r;
}

// ---------- CSR build ----------

// rank[e] = arrival order within dst bucket; cnt[i] ends as in-degree.
__global__ void k_cnt_rank(const int* __restrict__ dst, int* __restrict__ cnt,
                           int* __restrict__ rank, int E) {
    int e = blockIdx.x * blockDim.x + threadIdx.x;
    if (e < E) rank[e] = atomicAdd(&cnt[dst[e]], 1);
}

// order-free row allocation: block-local scan + atomic block base. One dispatch.
// rr[i] = (row_start, row_end)
__global__ void k_rowoff(const int* __restrict__ cnt, int2* __restrict__ rr,
                         int* __restrict__ gcur, int N) {
    __shared__ int sh[256];
    __shared__ int base;
    int t = threadIdx.x;
    int i = blockIdx.x * 256 + t;
    int v = (i < N) ? cnt[i] : 0;
    sh[t] = v;
    __syncthreads();
    for (int off = 1; off < 256; off <<= 1) {   // inclusive scan
        int u = (t >= off) ? sh[t - off] : 0;
        __syncthreads();
        sh[t] += u;
        __syncthreads();
    }
    if (t == 255) base = atomicAdd(gcur, sh[255]);
    __syncthreads();
    if (i < N) {
        int o = base + sh[t] - v;
        rr[i] = make_int2(o, o + v);
    }
}

// edge-parallel fill: coalesced reads, ONE scattered 8B store per edge.
__global__ void k_fillE(const int* __restrict__ src, const int* __restrict__ dst,
                        const float* __restrict__ w, const int* __restrict__ rank,
                        const int2* __restrict__ rr, int2* __restrict__ ev, int E) {
    int e = blockIdx.x * blockDim.x + threadIdx.x;
    if (e < E) {
        int pos = rr[dst[e]].x + rank[e];
        ev[pos] = make_int2(src[e], __float_as_int(w[e]));
    }
}

// weighted degree from CSR order; dis = rsqrt(deg) or 0
__global__ void k_deg_dis(const int2* __restrict__ rr, const int2* __restrict__ ev,
                          float* __restrict__ dis, int N) {
    int i = blockIdx.x * blockDim.x + threadIdx.x;
    if (i >= N) return;
    int2 se = rr[i];
    float dg = 0.f;
    for (int j = se.x; j < se.y; ++j) dg += __int_as_float(ev[j].y);
    dis[i] = (dg > 0.f) ? rsqrtf(dg) : 0.f;
}

// ev[j].y: w -> dis[dst]*w*dis[src], in place
__global__ void k_val(const int2* __restrict__ rr, const float* __restrict__ dis,
                      int2* __restrict__ ev, int N) {
    int i = blockIdx.x * blockDim.x + threadIdx.x;
    if (i >= N) return;
    int2 se = rr[i];
    float di = dis[i];
    for (int j = se.x; j < se.y; ++j) {
        int2 p = ev[j];
        ev[j].y = __float_as_int(di * __int_as_float(p.y) * dis[p.x]);
    }
}

// ---------- degree-sort: 64-bin counting sort of rows by in-degree ----------
// k_hist: per-block LDS histogram; block bin-chunk base via global atomic;
//   binrank[i] = rank of row i within its bin.
__global__ void k_hist(const int* __restrict__ cnt, int* __restrict__ binrank,
                       int* __restrict__ ghist, int N) {
    __shared__ int h[64];
    __shared__ int base[64];
    int t = threadIdx.x;
    if (t < 64) h[t] = 0;
    __syncthreads();
    int i = blockIdx.x * 256 + t;
    int b = 0, r = 0;
    if (i < N) {
        int c = cnt[i];
        b = (c < 63) ? c : 63;
        r = atomicAdd(&h[b], 1);
    }
    __syncthreads();
    if (t < 64) base[t] = h[t] ? atomicAdd(&ghist[t], h[t]) : 0;
    __syncthreads();
    if (i < N) binrank[i] = base[b] + r;
}

// exclusive scan of 64 bin counts (single wave)
__global__ void k_scan64(const int* __restrict__ ghist, int* __restrict__ gboff) {
    int l = threadIdx.x;           // 64 lanes
    int v = ghist[l];
    int s = v;
    for (int o = 1; o < 64; o <<= 1) {
        int u = __shfl_up(s, o);
        if (l >= o) s += u;
    }
    gboff[l] = s - v;
}

// perm[pos] = row, rrp[pos] = rr[row]; pos = bin base + rank-in-bin
__global__ void k_scatter(const int* __restrict__ cnt, const int* __restrict__ binrank,
                          const int* __restrict__ gboff, const int2* __restrict__ rr,
                          int* __restrict__ perm, int2* __restrict__ rrp, int N) {
    int i = blockIdx.x * blockDim.x + threadIdx.x;
    if (i >= N) return;
    int c = cnt[i];
    int b = (c < 63) ? c : 63;
    int pos = gboff[b] + binrank[i];
    perm[pos] = i;
    rrp[pos] = rr[i];
}

// fp32 -> bf16 row conversion (thread = 8 dims)
__global__ void k_cvt(const float4* __restrict__ x, uint4* __restrict__ xb, int n8) {
    int i = blockIdx.x * blockDim.x + threadIdx.x;
    if (i >= n8) return;
    float4 a = x[2 * i], b = x[2 * i + 1];
    float t[8] = {a.x, a.y, a.z, a.w, b.x, b.y, b.z, b.w};
    xb[i] = pack8(t);
}

// ---------- pull SpMM: 8-lane group per row (8 rows/wave), degree-sorted ----------
__global__ void k_spmm8(const int2* __restrict__ rrp, const int* __restrict__ perm,
                        const int2* __restrict__ ev, const uint4* __restrict__ xb,
                        uint4* __restrict__ xn, int N) {
    int idx = blockIdx.x * blockDim.x + threadIdx.x;
    int vrow = idx >> 3;
    if (vrow >= N) return;
    int g = idx & 7;
    int2 se = rrp[vrow];
    int row = perm[vrow];
    float acc[8] = {0.f, 0.f, 0.f, 0.f, 0.f, 0.f, 0.f, 0.f};
    int j = se.x, e = se.y;
    for (; j + 3 < e; j += 4) {           // unroll-4: 32 gathers in flight per wave
        int2 p0 = ev[j], p1 = ev[j + 1], p2 = ev[j + 2], p3 = ev[j + 3];
        uint4 a0 = xb[p0.x * 8 + g];
        uint4 a1 = xb[p1.x * 8 + g];
        uint4 a2 = xb[p2.x * 8 + g];
        uint4 a3 = xb[p3.x * 8 + g];
        bf8_fma(acc, a0, __int_as_float(p0.y));
        bf8_fma(acc, a1, __int_as_float(p1.y));
        bf8_fma(acc, a2, __int_as_float(p2.y));
        bf8_fma(acc, a3, __int_as_float(p3.y));
    }
    for (; j < e; ++j) {
        int2 p0 = ev[j];
        uint4 a0 = xb[p0.x * 8 + g];
        bf8_fma(acc, a0, __int_as_float(p0.y));
    }
    xn[row * 8 + g] = pack8(acc);
}

// final layer, fused epilogue: res = alpha*(x0 + x1 + x2 + A*x2)
// x0 consumed in bf16. out (fp32) optional; outb (bf16) optional.
__global__ void k_spmm8_final(const int2* __restrict__ rrp, const int* __restrict__ perm,
                              const int2* __restrict__ ev, const uint4* __restrict__ x2b,
                              const uint4* __restrict__ x1b, const uint4* __restrict__ x0b,
                              float4* __restrict__ out, uint4* __restrict__ outb,
                              float alpha, int N) {
    int idx = blockIdx.x * blockDim.x + threadIdx.x;
    int vrow = idx >> 3;
    if (vrow >= N) return;
    int g = idx & 7;
    int2 se = rrp[vrow];
    int row = perm[vrow];
    float acc[8] = {0.f, 0.f, 0.f, 0.f, 0.f, 0.f, 0.f, 0.f};
    int j = se.x, e = se.y;
    for (; j + 3 < e; j += 4) {
        int2 p0 = ev[j], p1 = ev[j + 1], p2 = ev[j + 2], p3 = ev[j + 3];
        uint4 a0 = x2b[p0.x * 8 + g];
        uint4 a1 = x2b[p1.x * 8 + g];
        uint4 a2 = x2b[p2.x * 8 + g];
        uint4 a3 = x2b[p3.x * 8 + g];
        bf8_fma(acc, a0, __int_as_float(p0.y));
        bf8_fma(acc, a1, __int_as_float(p1.y));
        bf8_fma(acc, a2, __int_as_float(p2.y));
        bf8_fma(acc, a3, __int_as_float(p3.y));
    }
    for (; j < e; ++j) {
        int2 p0 = ev[j];
        uint4 a0 = x2b[p0.x * 8 + g];
        bf8_fma(acc, a0, __int_as_float(p0.y));
    }
    bf8_add(acc, x1b[row * 8 + g]);       // + x1
    bf8_add(acc, x2b[row * 8 + g]);       // + x2
    bf8_add(acc, x0b[row * 8 + g]);       // + x0 (bf16)
    float r[8];
#pragma unroll
    for (int k = 0; k < 8; ++k) r[k] = alpha * acc[k];
    if (out) {
        out[row * 16 + 2 * g]     = make_float4(r[0], r[1], r[2], r[3]);
        out[row * 16 + 2 * g + 1] = make_float4(r[4], r[5], r[6], r[7]);
    }
    if (outb) outb[row * 8 + g] = pack8(r);
}

// ---------- host-side orchestration ----------

static void build_csr(const int* src, const int* dst, const float* w, int E, int N,
                      int2* ev, int* rank, int* cnt, int2* rr, float* dis,
                      int* perm, int2* rrp, hipStream_t stream) {
    const int B = 256;
    const int nbE = (E + B - 1) / B;
    const int nbN = (N + B - 1) / B;
    int* gcur  = cnt + N;                 // [1]
    int* ghist = cnt + N + 1;             // [64]
    int* gboff = cnt + N + 65;            // [64] (written by k_scan64, no memset)
    int* binrank = rank;                  // aliases rank; written after fillE consumed it
    hipMemsetAsync(cnt, 0, ((size_t)N + 65) * sizeof(int), stream);
    k_cnt_rank<<<nbE, B, 0, stream>>>(dst, cnt, rank, E);
    k_rowoff  <<<nbN, B, 0, stream>>>(cnt, rr, gcur, N);
    k_fillE   <<<nbE, B, 0, stream>>>(src, dst, w, rank, rr, ev, E);
    k_deg_dis <<<nbN, B, 0, stream>>>(rr, ev, dis, N);
    k_val     <<<nbN, B, 0, stream>>>(rr, dis, ev, N);
    k_hist    <<<nbN, B, 0, stream>>>(cnt, binrank, ghist, N);
    k_scan64  <<<1, 64, 0, stream>>>(ghist, gboff);
    k_scatter <<<nbN, B, 0, stream>>>(cnt, binrank, gboff, rr, perm, rrp, N);
}

extern "C" void kernel_launch(void* const* d_in, const int* in_sizes, int n_in,
                              void* d_out, int out_size, void* d_ws, size_t ws_size,
                              hipStream_t stream) {
    const float* emb_ii  = (const float*)d_in[0];
    const float* emb_uiu = (const float*)d_in[1];   // no longer mutated
    const float* w_ii    = (const float*)d_in[2];
    const float* w_uiu   = (const float*)d_in[3];
    const int*   src_ii  = (const int*)d_in[4];
    const int*   dst_ii  = src_ii + E_II;
    const int*   src_uiu = (const int*)d_in[5];
    const int*   dst_uiu = src_uiu + E_UIU;
    float*       out     = (float*)d_out;

    // workspace (~94.4 MB):
    //   xb0_u | x1_u | x2_u : 3 x N_UIU*8 uint4 (bf16 rows, 25.6MB each)
    //   ev [E_UIU int2] | rank [E_UIU int] | rr [N_UIU int2] | cnt [N_UIU+129] | dis [N_UIU]
    //   per-graph sort scratch (binrank/perm/rrp) aliases the rank block post-fillE.
    uint4* xb0_u = (uint4*)d_ws;
    uint4* x1_u  = xb0_u + (size_t)N_UIU * 8;
    uint4* x2_u  = x1_u + (size_t)N_UIU * 8;
    int2*  ev    = (int2*)(x2_u + (size_t)N_UIU * 8);
    int*   rank  = (int*)(ev + E_UIU);
    int2*  rr    = (int2*)(rank + E_UIU);
    int*   cnt   = (int*)(rr + N_UIU);
    float* dis   = (float*)(cnt + N_UIU + 129);

    uint4* g1_x0 = x1_u;                              // 12.8MB
    uint4* g1_x1 = x1_u + (size_t)N_II * 8;           // 12.8MB
    uint4* g1_x2 = x2_u;                              // 12.8MB

    const int B = 256;
    const float alpha = 0.25f;   // 1/(L+1), L=3 for both graphs

    // ================= item-item graph =================
    {
        int*  perm = rank + N_II;                     // aliases rank block
        int2* rrp  = (int2*)(rank + 2 * N_II);
        build_csr(src_ii, dst_ii, w_ii, E_II, N_II, ev, rank, cnt, rr, dis,
                  perm, rrp, stream);
        const int n8 = N_II * 8;
        const int ng = (n8 + B - 1) / B;
        uint4* hii_b = xb0_u + (size_t)N_USERS * 8;   // bf16 result -> graph2 x0 item block
        k_cvt  <<<ng, B, 0, stream>>>((const float4*)emb_ii, g1_x0, n8);
        k_spmm8<<<ng, B, 0, stream>>>(rrp, perm, ev, g1_x0, g1_x1, N_II);
        k_spmm8<<<ng, B, 0, stream>>>(rrp, perm, ev, g1_x1, g1_x2, N_II);
        k_spmm8_final<<<ng, B, 0, stream>>>(rrp, perm, ev, g1_x2, g1_x1, g1_x0,
                                            nullptr, hii_b, alpha, N_II);
    }

    // ================= user-item graph =================
    {
        int*  perm = rank + N_UIU;
        int2* rrp  = (int2*)(rank + 2 * N_UIU);
        build_csr(src_uiu, dst_uiu, w_uiu, E_UIU, N_UIU, ev, rank, cnt, rr, dis,
                  perm, rrp, stream);
        // convert only the user half of x0; item half written bf16 by graph1 final
        const int n8u = N_USERS * 8;
        k_cvt<<<(n8u + B - 1) / B, B, 0, stream>>>((const float4*)emb_uiu, xb0_u, n8u);
        const int n8 = N_UIU * 8;
        const int ng = (n8 + B - 1) / B;
        k_spmm8<<<ng, B, 0, stream>>>(rrp, perm, ev, xb0_u, x1_u, N_UIU);
        k_spmm8<<<ng, B, 0, stream>>>(rrp, perm, ev, x1_u, x2_u, N_UIU);
        k_spmm8_final<<<ng, B, 0, stream>>>(rrp, perm, ev, x2_u, x1_u, xb0_u,
                                            (float4*)out, nullptr, alpha, N_UIU);
    }
}

// Round 2
// 498.493 us; speedup vs baseline: 1.0258x; 1.0258x over previous
//
#include <hip/hip_runtime.h>

// BigraphLightModel — R7: latency-chain batching + build fusion.
//   R6 profile: k_cnt_rank is #1 (2x ~49.5us, VALU 0.5%, HBM 11%) — each
//   thread does ONE edge: load dst -> dependent atomicAdd(return) -> store,
//   wave lifetime ~1.4us for 64 edges => wave-lifetime latency bound.
//   This round:
//    (a) k_cnt_rank: K=8 edges/thread, batched coalesced loads then 8
//        independent atomics in flight per thread (8x work per wave-slot).
//    (b) k_fillE: K=4 edges/thread, same ILP treatment of the rr-gather +
//        scattered-store chain.
//    (c) fuse k_hist into k_deg_dis (bin = rr.y-rr.x, no cnt re-read) and
//        k_scatter into k_val — build drops 8 -> 6 dispatches, -2 N-sweeps.
//   SpMM (degree-sorted since R6) untouched this round.

#define D       64
#define N_II    100000
#define N_UIU   200000
#define E_II    600000
#define E_UIU   1200000
#define N_USERS 100000

// ---------- bf16 helpers ----------
__device__ __forceinline__ unsigned short f2bf(float f) {
    unsigned u = __float_as_uint(f);
    u += 0x7fffu + ((u >> 16) & 1u);          // round-to-nearest-even
    return (unsigned short)(u >> 16);
}
__device__ __forceinline__ void bf8_fma(float acc[8], uint4 p, float v) {
    acc[0] += v * __uint_as_float(p.x << 16);
    acc[1] += v * __uint_as_float(p.x & 0xffff0000u);
    acc[2] += v * __uint_as_float(p.y << 16);
    acc[3] += v * __uint_as_float(p.y & 0xffff0000u);
    acc[4] += v * __uint_as_float(p.z << 16);
    acc[5] += v * __uint_as_float(p.z & 0xffff0000u);
    acc[6] += v * __uint_as_float(p.w << 16);
    acc[7] += v * __uint_as_float(p.w & 0xffff0000u);
}
__device__ __forceinline__ void bf8_add(float acc[8], uint4 p) {
    acc[0] += __uint_as_float(p.x << 16);
    acc[1] += __uint_as_float(p.x & 0xffff0000u);
    acc[2] += __uint_as_float(p.y << 16);
    acc[3] += __uint_as_float(p.y & 0xffff0000u);
    acc[4] += __uint_as_float(p.z << 16);
    acc[5] += __uint_as_float(p.z & 0xffff0000u);
    acc[6] += __uint_as_float(p.w << 16);
    acc[7] += __uint_as_float(p.w & 0xffff0000u);
}
__device__ __forceinline__ uint4 pack8(const float a[8]) {
    uint4 r;
    r.x = (unsigned)f2bf(a[0]) | ((unsigned)f2bf(a[1]) << 16);
    r.y = (unsigned)f2bf(a[2]) | ((unsigned)f2bf(a[3]) << 16);
    r.z = (unsigned)f2bf(a[4]) | ((unsigned)f2bf(a[5]) << 16);
    r.w = (unsigned)f2bf(a[6]) | ((unsigned)f2bf(a[7]) << 16);
    return r;
}

// ---------- CSR build ----------

// rank[e] = arrival order within dst bucket; cnt[i] ends as in-degree.
// K=8 edges/thread: batched loads, 8 independent atomics in flight.
#define CR_K 8
__global__ void k_cnt_rank(const int* __restrict__ dst, int* __restrict__ cnt,
                           int* __restrict__ rank, int E) {
    int base = blockIdx.x * (blockDim.x * CR_K) + threadIdx.x;
    int d[CR_K];
#pragma unroll
    for (int k = 0; k < CR_K; ++k) {
        int e = base + k * blockDim.x;
        d[k] = (e < E) ? dst[e] : 0;
    }
#pragma unroll
    for (int k = 0; k < CR_K; ++k) {
        int e = base + k * blockDim.x;
        if (e < E) rank[e] = atomicAdd(&cnt[d[k]], 1);
    }
}

// order-free row allocation: block-local scan + atomic block base. One dispatch.
// rr[i] = (row_start, row_end)
__global__ void k_rowoff(const int* __restrict__ cnt, int2* __restrict__ rr,
                         int* __restrict__ gcur, int N) {
    __shared__ int sh[256];
    __shared__ int base;
    int t = threadIdx.x;
    int i = blockIdx.x * 256 + t;
    int v = (i < N) ? cnt[i] : 0;
    sh[t] = v;
    __syncthreads();
    for (int off = 1; off < 256; off <<= 1) {   // inclusive scan
        int u = (t >= off) ? sh[t - off] : 0;
        __syncthreads();
        sh[t] += u;
        __syncthreads();
    }
    if (t == 255) base = atomicAdd(gcur, sh[255]);
    __syncthreads();
    if (i < N) {
        int o = base + sh[t] - v;
        rr[i] = make_int2(o, o + v);
    }
}

// edge-parallel fill: coalesced reads, ONE scattered 8B store per edge.
// K=4 edges/thread: overlap the rr-gather + scattered-store chains.
#define FE_K 4
__global__ void k_fillE(const int* __restrict__ src, const int* __restrict__ dst,
                        const float* __restrict__ w, const int* __restrict__ rank,
                        const int2* __restrict__ rr, int2* __restrict__ ev, int E) {
    int base = blockIdx.x * (blockDim.x * FE_K) + threadIdx.x;
    int d[FE_K], r[FE_K], s[FE_K];
    float ww[FE_K];
#pragma unroll
    for (int k = 0; k < FE_K; ++k) {
        int e = base + k * blockDim.x;
        if (e < E) { d[k] = dst[e]; r[k] = rank[e]; s[k] = src[e]; ww[k] = w[e]; }
        else       { d[k] = 0; r[k] = 0; s[k] = 0; ww[k] = 0.f; }
    }
    int pos[FE_K];
#pragma unroll
    for (int k = 0; k < FE_K; ++k) pos[k] = rr[d[k]].x + r[k];
#pragma unroll
    for (int k = 0; k < FE_K; ++k) {
        int e = base + k * blockDim.x;
        if (e < E) ev[pos[k]] = make_int2(s[k], __float_as_int(ww[k]));
    }
}

// fused: weighted degree -> dis = rsqrt(deg); 64-bin degree histogram
// (bin from rr.y-rr.x, no cnt read) with LDS privatization; binrank[i].
__global__ void k_deg_hist(const int2* __restrict__ rr, const int2* __restrict__ ev,
                           float* __restrict__ dis, int* __restrict__ binrank,
                           int* __restrict__ ghist, int N) {
    __shared__ int h[64];
    __shared__ int hbase[64];
    int t = threadIdx.x;
    if (t < 64) h[t] = 0;
    __syncthreads();
    int i = blockIdx.x * 256 + t;
    int b = 0, rk = 0;
    if (i < N) {
        int2 se = rr[i];
        float dg = 0.f;
        for (int j = se.x; j < se.y; ++j) dg += __int_as_float(ev[j].y);
        dis[i] = (dg > 0.f) ? rsqrtf(dg) : 0.f;
        int c = se.y - se.x;
        b = (c < 63) ? c : 63;
        rk = atomicAdd(&h[b], 1);
    }
    __syncthreads();
    if (t < 64) hbase[t] = h[t] ? atomicAdd(&ghist[t], h[t]) : 0;
    __syncthreads();
    if (i < N) binrank[i] = hbase[b] + rk;
}

// exclusive scan of 64 bin counts (single wave)
__global__ void k_scan64(const int* __restrict__ ghist, int* __restrict__ gboff) {
    int l = threadIdx.x;           // 64 lanes
    int v = ghist[l];
    int s = v;
    for (int o = 1; o < 64; o <<= 1) {
        int u = __shfl_up(s, o);
        if (l >= o) s += u;
    }
    gboff[l] = s - v;
}

// fused: ev[j].y: w -> dis[dst]*w*dis[src] in place; scatter degree-sorted
// row permutation: perm[pos]=row, rrp[pos]=rr[row].
__global__ void k_val_scatter(const int2* __restrict__ rr, const float* __restrict__ dis,
                              const int* __restrict__ binrank, const int* __restrict__ gboff,
                              int2* __restrict__ ev, int* __restrict__ perm,
                              int2* __restrict__ rrp, int N) {
    int i = blockIdx.x * blockDim.x + threadIdx.x;
    if (i >= N) return;
    int2 se = rr[i];
    float di = dis[i];
    for (int j = se.x; j < se.y; ++j) {
        int2 p = ev[j];
        ev[j].y = __float_as_int(di * __int_as_float(p.y) * dis[p.x]);
    }
    int c = se.y - se.x;
    int b = (c < 63) ? c : 63;
    int pos = gboff[b] + binrank[i];
    perm[pos] = i;
    rrp[pos]  = rr[i];
}

// fp32 -> bf16 row conversion (thread = 8 dims)
__global__ void k_cvt(const float4* __restrict__ x, uint4* __restrict__ xb, int n8) {
    int i = blockIdx.x * blockDim.x + threadIdx.x;
    if (i >= n8) return;
    float4 a = x[2 * i], b = x[2 * i + 1];
    float t[8] = {a.x, a.y, a.z, a.w, b.x, b.y, b.z, b.w};
    xb[i] = pack8(t);
}

// ---------- pull SpMM: 8-lane group per row (8 rows/wave), degree-sorted ----------
__global__ void k_spmm8(const int2* __restrict__ rrp, const int* __restrict__ perm,
                        const int2* __restrict__ ev, const uint4* __restrict__ xb,
                        uint4* __restrict__ xn, int N) {
    int idx = blockIdx.x * blockDim.x + threadIdx.x;
    int vrow = idx >> 3;
    if (vrow >= N) return;
    int g = idx & 7;
    int2 se = rrp[vrow];
    int row = perm[vrow];
    float acc[8] = {0.f, 0.f, 0.f, 0.f, 0.f, 0.f, 0.f, 0.f};
    int j = se.x, e = se.y;
    for (; j + 3 < e; j += 4) {           // unroll-4: 32 gathers in flight per wave
        int2 p0 = ev[j], p1 = ev[j + 1], p2 = ev[j + 2], p3 = ev[j + 3];
        uint4 a0 = xb[p0.x * 8 + g];
        uint4 a1 = xb[p1.x * 8 + g];
        uint4 a2 = xb[p2.x * 8 + g];
        uint4 a3 = xb[p3.x * 8 + g];
        bf8_fma(acc, a0, __int_as_float(p0.y));
        bf8_fma(acc, a1, __int_as_float(p1.y));
        bf8_fma(acc, a2, __int_as_float(p2.y));
        bf8_fma(acc, a3, __int_as_float(p3.y));
    }
    for (; j < e; ++j) {
        int2 p0 = ev[j];
        uint4 a0 = xb[p0.x * 8 + g];
        bf8_fma(acc, a0, __int_as_float(p0.y));
    }
    xn[row * 8 + g] = pack8(acc);
}

// final layer, fused epilogue: res = alpha*(x0 + x1 + x2 + A*x2)
// x0 consumed in bf16. out (fp32) optional; outb (bf16) optional.
__global__ void k_spmm8_final(const int2* __restrict__ rrp, const int* __restrict__ perm,
                              const int2* __restrict__ ev, const uint4* __restrict__ x2b,
                              const uint4* __restrict__ x1b, const uint4* __restrict__ x0b,
                              float4* __restrict__ out, uint4* __restrict__ outb,
                              float alpha, int N) {
    int idx = blockIdx.x * blockDim.x + threadIdx.x;
    int vrow = idx >> 3;
    if (vrow >= N) return;
    int g = idx & 7;
    int2 se = rrp[vrow];
    int row = perm[vrow];
    float acc[8] = {0.f, 0.f, 0.f, 0.f, 0.f, 0.f, 0.f, 0.f};
    int j = se.x, e = se.y;
    for (; j + 3 < e; j += 4) {
        int2 p0 = ev[j], p1 = ev[j + 1], p2 = ev[j + 2], p3 = ev[j + 3];
        uint4 a0 = x2b[p0.x * 8 + g];
        uint4 a1 = x2b[p1.x * 8 + g];
        uint4 a2 = x2b[p2.x * 8 + g];
        uint4 a3 = x2b[p3.x * 8 + g];
        bf8_fma(acc, a0, __int_as_float(p0.y));
        bf8_fma(acc, a1, __int_as_float(p1.y));
        bf8_fma(acc, a2, __int_as_float(p2.y));
        bf8_fma(acc, a3, __int_as_float(p3.y));
    }
    for (; j < e; ++j) {
        int2 p0 = ev[j];
        uint4 a0 = x2b[p0.x * 8 + g];
        bf8_fma(acc, a0, __int_as_float(p0.y));
    }
    bf8_add(acc, x1b[row * 8 + g]);       // + x1
    bf8_add(acc, x2b[row * 8 + g]);       // + x2
    bf8_add(acc, x0b[row * 8 + g]);       // + x0 (bf16)
    float r[8];
#pragma unroll
    for (int k = 0; k < 8; ++k) r[k] = alpha * acc[k];
    if (out) {
        out[row * 16 + 2 * g]     = make_float4(r[0], r[1], r[2], r[3]);
        out[row * 16 + 2 * g + 1] = make_float4(r[4], r[5], r[6], r[7]);
    }
    if (outb) outb[row * 8 + g] = pack8(r);
}

// ---------- host-side orchestration ----------

static void build_csr(const int* src, const int* dst, const float* w, int E, int N,
                      int2* ev, int* rank, int* cnt, int2* rr, float* dis,
                      int* perm, int2* rrp, hipStream_t stream) {
    const int B = 256;
    const int nbN = (N + B - 1) / B;
    const int nbE_cr = (E + B * CR_K - 1) / (B * CR_K);
    const int nbE_fe = (E + B * FE_K - 1) / (B * FE_K);
    int* gcur  = cnt + N;                 // [1]
    int* ghist = cnt + N + 1;             // [64]
    int* gboff = cnt + N + 65;            // [64] (written by k_scan64, no memset)
    int* binrank = rank;                  // aliases rank; written after fillE consumed it
    hipMemsetAsync(cnt, 0, ((size_t)N + 65) * sizeof(int), stream);
    k_cnt_rank   <<<nbE_cr, B, 0, stream>>>(dst, cnt, rank, E);
    k_rowoff     <<<nbN, B, 0, stream>>>(cnt, rr, gcur, N);
    k_fillE      <<<nbE_fe, B, 0, stream>>>(src, dst, w, rank, rr, ev, E);
    k_deg_hist   <<<nbN, B, 0, stream>>>(rr, ev, dis, binrank, ghist, N);
    k_scan64     <<<1, 64, 0, stream>>>(ghist, gboff);
    k_val_scatter<<<nbN, B, 0, stream>>>(rr, dis, binrank, gboff, ev, perm, rrp, N);
}

extern "C" void kernel_launch(void* const* d_in, const int* in_sizes, int n_in,
                              void* d_out, int out_size, void* d_ws, size_t ws_size,
                              hipStream_t stream) {
    const float* emb_ii  = (const float*)d_in[0];
    const float* emb_uiu = (const float*)d_in[1];
    const float* w_ii    = (const float*)d_in[2];
    const float* w_uiu   = (const float*)d_in[3];
    const int*   src_ii  = (const int*)d_in[4];
    const int*   dst_ii  = src_ii + E_II;
    const int*   src_uiu = (const int*)d_in[5];
    const int*   dst_uiu = src_uiu + E_UIU;
    float*       out     = (float*)d_out;

    // workspace (~94.4 MB):
    //   xb0_u | x1_u | x2_u : 3 x N_UIU*8 uint4 (bf16 rows, 25.6MB each)
    //   ev [E_UIU int2] | rank [E_UIU int] | rr [N_UIU int2] | cnt [N_UIU+129] | dis [N_UIU]
    //   per-graph sort scratch (binrank/perm/rrp) aliases the rank block post-fillE.
    uint4* xb0_u = (uint4*)d_ws;
    uint4* x1_u  = xb0_u + (size_t)N_UIU * 8;
    uint4* x2_u  = x1_u + (size_t)N_UIU * 8;
    int2*  ev    = (int2*)(x2_u + (size_t)N_UIU * 8);
    int*   rank  = (int*)(ev + E_UIU);
    int2*  rr    = (int2*)(rank + E_UIU);
    int*   cnt   = (int*)(rr + N_UIU);
    float* dis   = (float*)(cnt + N_UIU + 129);

    uint4* g1_x0 = x1_u;                              // 12.8MB
    uint4* g1_x1 = x1_u + (size_t)N_II * 8;           // 12.8MB
    uint4* g1_x2 = x2_u;                              // 12.8MB

    const int B = 256;
    const float alpha = 0.25f;   // 1/(L+1), L=3 for both graphs

    // ================= item-item graph =================
    {
        int*  perm = rank + N_II;                     // aliases rank block
        int2* rrp  = (int2*)(rank + 2 * N_II);
        build_csr(src_ii, dst_ii, w_ii, E_II, N_II, ev, rank, cnt, rr, dis,
                  perm, rrp, stream);
        const int n8 = N_II * 8;
        const int ng = (n8 + B - 1) / B;
        uint4* hii_b = xb0_u + (size_t)N_USERS * 8;   // bf16 result -> graph2 x0 item block
        k_cvt  <<<ng, B, 0, stream>>>((const float4*)emb_ii, g1_x0, n8);
        k_spmm8<<<ng, B, 0, stream>>>(rrp, perm, ev, g1_x0, g1_x1, N_II);
        k_spmm8<<<ng, B, 0, stream>>>(rrp, perm, ev, g1_x1, g1_x2, N_II);
        k_spmm8_final<<<ng, B, 0, stream>>>(rrp, perm, ev, g1_x2, g1_x1, g1_x0,
                                            nullptr, hii_b, alpha, N_II);
    }

    // ================= user-item graph =================
    {
        int*  perm = rank + N_UIU;
        int2* rrp  = (int2*)(rank + 2 * N_UIU);
        build_csr(src_uiu, dst_uiu, w_uiu, E_UIU, N_UIU, ev, rank, cnt, rr, dis,
                  perm, rrp, stream);
        // convert only the user half of x0; item half written bf16 by graph1 final
        const int n8u = N_USERS * 8;
        k_cvt<<<(n8u + B - 1) / B, B, 0, stream>>>((const float4*)emb_uiu, xb0_u, n8u);
        const int n8 = N_UIU * 8;
        const int ng = (n8 + B - 1) / B;
        k_spmm8<<<ng, B, 0, stream>>>(rrp, perm, ev, xb0_u, x1_u, N_UIU);
        k_spmm8<<<ng, B, 0, stream>>>(rrp, perm, ev, x1_u, x2_u, N_UIU);
        k_spmm8_final<<<ng, B, 0, stream>>>(rrp, perm, ev, x2_u, x1_u, xb0_u,
                                            (float4*)out, nullptr, alpha, N_UIU);
    }
}